// Round 17
// baseline (212.455 us; speedup 1.0000x reference)
//
#include <hip/hip_runtime.h>
#include <hip/hip_bf16.h>
#include <stdint.h>

#define T_STEPS 16
#define BATCH   16
#define CHANNELS 32
#define HGT 128
#define WID 128
#define HW (HGT*WID)      // 16384
#define KSEL 8192         // ascending 0-based rank of threshold = N - k
#define CAP 1024          // candidate buffer (safety)
#define SMALL 128         // stop narrowing when candidate set <= SMALL
#define NB 4096           // histogram bins
#define NBS 1024.0f       // initial scale: 4096 bins over [0,4)

typedef float vfloat4 __attribute__((ext_vector_type(4)));

__device__ __forceinline__ vfloat4 v4max(vfloat4 a, vfloat4 b) {
    vfloat4 r;
    r.x = fmaxf(a.x, b.x); r.y = fmaxf(a.y, b.y);
    r.z = fmaxf(a.z, b.z); r.w = fmaxf(a.w, b.w);
    return r;
}

__device__ __forceinline__ uint32_t wave_incl_scan(uint32_t v, int lane) {
    #pragma unroll
    for (int off = 1; off < 64; off <<= 1) {
        uint32_t u = __shfl_up(v, off, 64);
        if (lane >= off) v += u;
    }
    return v;
}

// LDS-only barrier: drain DS ops, keep global loads in flight.
__device__ __forceinline__ void lds_barrier() {
    asm volatile("s_waitcnt lgkmcnt(0)" ::: "memory");
    __builtin_amdgcn_s_barrier();
}

// ---------- kernel 1: pool v2-NT — measured best (118 us, r5 subtraction) ----------
__global__ __launch_bounds__(256)
void pool_max_kernel(const float* __restrict__ x, float* __restrict__ pooled) {
    int tid  = blockIdx.x * blockDim.x + threadIdx.x;
    int base = tid * 4;
    int tb   = base >> 14;
    int pix  = base & (HW - 1);
    const vfloat4* src = (const vfloat4*)(x + (size_t)tb * CHANNELS * HW + pix);
    vfloat4 a0 = __builtin_nontemporal_load(src + 0 * (HW/4));
    vfloat4 a1 = __builtin_nontemporal_load(src + 1 * (HW/4));
    vfloat4 a2 = __builtin_nontemporal_load(src + 2 * (HW/4));
    vfloat4 a3 = __builtin_nontemporal_load(src + 3 * (HW/4));
    #pragma unroll
    for (int c = 4; c < CHANNELS; c += 4) {
        a0 = v4max(a0, __builtin_nontemporal_load(src + (size_t)(c+0) * (HW/4)));
        a1 = v4max(a1, __builtin_nontemporal_load(src + (size_t)(c+1) * (HW/4)));
        a2 = v4max(a2, __builtin_nontemporal_load(src + (size_t)(c+2) * (HW/4)));
        a3 = v4max(a3, __builtin_nontemporal_load(src + (size_t)(c+3) * (HW/4)));
    }
    *(vfloat4*)(pooled + base) = v4max(v4max(a0, a1), v4max(a2, a3));
}

// ---------- kernel 2: lif0 v4 — measured ~37 us (16-CU read-BW floor) ----------
__global__ __launch_bounds__(1024)
void lif0_kernel(const float* __restrict__ pooled, uint8_t* __restrict__ spk) {
    __shared__ uint32_t hist[NB];
    __shared__ uint32_t s_wtot[16];
    __shared__ float    col[CAP];
    __shared__ uint32_t s_sel[4];
    __shared__ float    s_thr;

    const int b    = blockIdx.x;
    const int tid  = threadIdx.x;
    const int wid  = tid >> 6;
    const int lane = tid & 63;

    float m[16];
    #pragma unroll
    for (int i = 0; i < 16; ++i) m[i] = 0.0f;

    hist[tid] = 0; hist[tid + 1024] = 0; hist[tid + 2048] = 0; hist[tid + 3072] = 0;

    const float4* p0 = (const float4*)(pooled + (size_t)b * HW);
    float4 x0 = p0[tid], x1 = p0[1024 + tid], x2 = p0[2048 + tid], x3 = p0[3072 + tid];

    lds_barrier();

    for (int t = 0; t < T_STEPS; ++t) {
        m[ 0] = 0.25f * m[ 0] + x0.x;  m[ 1] = 0.25f * m[ 1] + x0.y;
        m[ 2] = 0.25f * m[ 2] + x0.z;  m[ 3] = 0.25f * m[ 3] + x0.w;
        m[ 4] = 0.25f * m[ 4] + x1.x;  m[ 5] = 0.25f * m[ 5] + x1.y;
        m[ 6] = 0.25f * m[ 6] + x1.z;  m[ 7] = 0.25f * m[ 7] + x1.w;
        m[ 8] = 0.25f * m[ 8] + x2.x;  m[ 9] = 0.25f * m[ 9] + x2.y;
        m[10] = 0.25f * m[10] + x2.z;  m[11] = 0.25f * m[11] + x2.w;
        m[12] = 0.25f * m[12] + x3.x;  m[13] = 0.25f * m[13] + x3.y;
        m[14] = 0.25f * m[14] + x3.z;  m[15] = 0.25f * m[15] + x3.w;

        if (t + 1 < T_STEPS) {
            const float4* pn = (const float4*)(pooled + ((size_t)(t+1) * BATCH + b) * HW);
            x0 = pn[tid]; x1 = pn[1024 + tid]; x2 = pn[2048 + tid]; x3 = pn[3072 + tid];
        }

        float    rlo   = 0.0f;
        float    sc    = NBS;
        uint32_t r     = KSEL;
        uint32_t cnt   = HW;
        uint32_t amask = 0xFFFFu;
        for (int iter = 0;; ++iter) {
            #pragma unroll
            for (int i = 0; i < 16; ++i) {
                if (amask & (1u << i)) {
                    int bn = (int)((m[i] - rlo) * sc);
                    bn = min(max(bn, 0), NB - 1);
                    atomicAdd(&hist[bn], 1u);
                }
            }
            lds_barrier();                               // A
            uint4 hc = *(const uint4*)&hist[tid * 4];
            uint4 z; z.x = z.y = z.z = z.w = 0u;
            *(uint4*)&hist[tid * 4] = z;                 // fold clear
            uint32_t psum = hc.x + hc.y + hc.z + hc.w;
            uint32_t incl = wave_incl_scan(psum, lane);
            if (lane == 63) s_wtot[wid] = incl;
            lds_barrier();                               // B
            uint32_t wbase = 0;
            for (int w = 0; w < wid; ++w) wbase += s_wtot[w];
            uint32_t excl = wbase + incl - psum;
            if (tid == 0) s_sel[3] = 0;
            if (r >= excl && r < excl + psum) {
                uint32_t acc = excl; int dsel = -1; uint32_t nr = 0, nc = 0;
                if (r < acc + hc.x) { dsel = tid*4+0; nr = r-acc; nc = hc.x; } acc += hc.x;
                if (dsel < 0 && r < acc + hc.y) { dsel = tid*4+1; nr = r-acc; nc = hc.y; } acc += hc.y;
                if (dsel < 0 && r < acc + hc.z) { dsel = tid*4+2; nr = r-acc; nc = hc.z; } acc += hc.z;
                if (dsel < 0 && r < acc + hc.w) { dsel = tid*4+3; nr = r-acc; nc = hc.w; }
                s_sel[0] = (uint32_t)dsel; s_sel[1] = nr; s_sel[2] = nc;
            }
            lds_barrier();                               // C
            const int jsel = (int)s_sel[0];
            r = s_sel[1]; cnt = s_sel[2];
            uint32_t nm = 0;
            #pragma unroll
            for (int i = 0; i < 16; ++i) {
                if (amask & (1u << i)) {
                    int bn = (int)((m[i] - rlo) * sc);
                    bn = min(max(bn, 0), NB - 1);
                    if (bn == jsel) nm |= (1u << i);
                }
            }
            amask = nm;
            rlo += (float)jsel / sc;
            sc  *= (float)NB;
            if (cnt <= SMALL || iter >= 3) break;
        }

        #pragma unroll
        for (int i = 0; i < 16; ++i) {
            if (amask & (1u << i)) {
                uint32_t u = atomicAdd(&s_sel[3], 1u);
                if (u < CAP) col[u] = m[i];
            }
        }
        lds_barrier();                                   // D
        {
            uint32_t ncol = min(cnt, (uint32_t)CAP);
            for (uint32_t j = tid; j < ncol; j += 1024) {
                float v = col[j];
                uint32_t less = 0, leq = 0;
                for (uint32_t i2 = 0; i2 < ncol; ++i2) {
                    float u = col[i2];
                    less += (u < v);
                    leq  += (u <= v);
                }
                if (less <= r && r < leq) s_thr = v;     // k-th largest, exact bits
            }
        }
        lds_barrier();                                   // E
        const float thr = s_thr;

        uchar4* so4 = (uchar4*)(spk + ((size_t)t * BATCH + b) * HW);
        #pragma unroll
        for (int i = 0; i < 4; ++i) {
            uchar4 s4;
            s4.x = (m[i*4+0] >= thr) ? 1 : 0;
            s4.y = (m[i*4+1] >= thr) ? 1 : 0;
            s4.z = (m[i*4+2] >= thr) ? 1 : 0;
            s4.w = (m[i*4+3] >= thr) ? 1 : 0;
            if (s4.x) m[i*4+0] = 0.0f;
            if (s4.y) m[i*4+1] = 0.0f;
            if (s4.z) m[i*4+2] = 0.0f;
            if (s4.w) m[i*4+3] = 0.0f;
            so4[i * 1024 + tid] = s4;
        }
    }
}

// ---------- kernel 3: conv v6 — measured best (18.5 us, r12 counters) ----------
__global__ __launch_bounds__(256)
void conv_lif1_kernel(const uint8_t* __restrict__ spk, const float* __restrict__ wconv,
                      float* __restrict__ out_spike, float* __restrict__ out_mem) {
    const int s   = blockIdx.x * 256 + threadIdx.x;  // 0..65535
    const int b   = s >> 12;
    const int rem = s & 4095;
    const int r   = rem >> 5;          // 0..127
    const int c0  = (rem & 31) << 2;   // 0,4,...,124

    float w[49];
    #pragma unroll
    for (int i = 0; i < 49; ++i) w[i] = wconv[i];   // uniform -> SGPRs

    float m0 = 0.f, m1 = 0.f, m2 = 0.f, m3 = 0.f;
    for (int t = 0; t < T_STEPS; ++t) {
        const uint8_t* sb = spk + (((size_t)t * BATCH + b) << 14);
        float a0 = 0.f, a1 = 0.f, a2 = 0.f, a3 = 0.f;
        #pragma unroll
        for (int dy = 0; dy < 7; ++dy) {
            int gr = r + dy - 3;
            uint32_t u0 = 0, u1 = 0, u2 = 0;
            if ((unsigned)gr < (unsigned)HGT) {
                const uint8_t* rp = sb + (gr << 7);
                if (c0 > 0)   u0 = *(const uint32_t*)(rp + c0 - 4);
                u1 = *(const uint32_t*)(rp + c0);
                if (c0 < 124) u2 = *(const uint32_t*)(rp + c0 + 4);
            }
            float win[10];
            win[0] = (float)((u0 >>  8) & 255u);
            win[1] = (float)((u0 >> 16) & 255u);
            win[2] = (float)((u0 >> 24));
            win[3] = (float)( u1         & 255u);
            win[4] = (float)((u1 >>  8) & 255u);
            win[5] = (float)((u1 >> 16) & 255u);
            win[6] = (float)((u1 >> 24));
            win[7] = (float)( u2         & 255u);
            win[8] = (float)((u2 >>  8) & 255u);
            win[9] = (float)((u2 >> 16) & 255u);
            #pragma unroll
            for (int dx = 0; dx < 7; ++dx) {
                float wv = w[dy * 7 + dx];
                a0 = fmaf(win[dx + 0], wv, a0);
                a1 = fmaf(win[dx + 1], wv, a1);
                a2 = fmaf(win[dx + 2], wv, a2);
                a3 = fmaf(win[dx + 3], wv, a3);
            }
        }
        float n0 = 0.25f * m0 + a0;
        float n1 = 0.25f * m1 + a1;
        float n2 = 0.25f * m2 + a2;
        float n3 = 0.25f * m3 + a3;
        float s0 = (n0 > 1.0f) ? 1.0f : 0.0f;
        float s1 = (n1 > 1.0f) ? 1.0f : 0.0f;
        float s2 = (n2 > 1.0f) ? 1.0f : 0.0f;
        float s3 = (n3 > 1.0f) ? 1.0f : 0.0f;
        size_t o = (((size_t)t * BATCH + b) << 14) + ((size_t)r << 7) + c0;
        vfloat4 sv = {s0, s1, s2, s3};
        vfloat4 mv = {n0, n1, n2, n3};
        *(vfloat4*)(out_spike + o) = sv;
        *(vfloat4*)(out_mem   + o) = mv;
        m0 = n0 - s0; m1 = n1 - s1; m2 = n2 - s2; m3 = n3 - s3;
    }
}

extern "C" void kernel_launch(void* const* d_in, const int* in_sizes, int n_in,
                              void* d_out, int out_size, void* d_ws, size_t ws_size,
                              hipStream_t stream) {
    const float* x     = (const float*)d_in[0];
    const float* wconv = (const float*)d_in[1];
    float* out = (float*)d_out;

    const size_t n_pooled = (size_t)T_STEPS * BATCH * HW;
    float*   pooled = (float*)d_ws;
    uint8_t* spk    = (uint8_t*)d_ws + n_pooled * sizeof(float);

    pool_max_kernel<<<4096, 256, 0, stream>>>(x, pooled);
    lif0_kernel<<<BATCH, 1024, 0, stream>>>(pooled, spk);
    conv_lif1_kernel<<<256, 256, 0, stream>>>(spk, wconv, out, out + n_pooled);
}

// Round 18
// 194.065 us; speedup vs baseline: 1.0948x; 1.0948x over previous
//
#include <hip/hip_runtime.h>
#include <hip/hip_bf16.h>
#include <stdint.h>

#define T_STEPS 16
#define BATCH   16
#define CHANNELS 32
#define HGT 128
#define WID 128
#define HW (HGT*WID)      // 16384
#define KSEL 8192         // ascending 0-based rank of threshold = N - k
#define CAP 1024          // candidate buffer (safety)
#define SMALL 128         // stop narrowing when candidate set <= SMALL
#define NB 4096           // histogram bins
#define NBS 1024.0f       // initial scale: 4096 bins over [0,4)

typedef float vfloat4 __attribute__((ext_vector_type(4)));

__device__ __forceinline__ vfloat4 v4max(vfloat4 a, vfloat4 b) {
    vfloat4 r;
    r.x = fmaxf(a.x, b.x); r.y = fmaxf(a.y, b.y);
    r.z = fmaxf(a.z, b.z); r.w = fmaxf(a.w, b.w);
    return r;
}

__device__ __forceinline__ uint32_t wave_incl_scan(uint32_t v, int lane) {
    #pragma unroll
    for (int off = 1; off < 64; off <<= 1) {
        uint32_t u = __shfl_up(v, off, 64);
        if (lane >= off) v += u;
    }
    return v;
}

// LDS-only barrier: drain DS ops, keep global loads in flight.
__device__ __forceinline__ void lds_barrier() {
    asm volatile("s_waitcnt lgkmcnt(0)" ::: "memory");
    __builtin_amdgcn_s_barrier();
}

// ---------- kernel 1: pool v4 — sequential half-plane sweep, 2 blocks/CU ----------
// 512 blocks x 1024 thr (2 per (t,b)): v3's sequential-plane NT pattern at FULL
// occupancy (32 waves/CU, was 16). Block sweeps its 1 MB half-region
// channel-by-channel, 32 KB contiguous per channel iteration.
__global__ __launch_bounds__(1024)
void pool_max_kernel(const float* __restrict__ x, float* __restrict__ pooled) {
    const int s   = blockIdx.x >> 1;             // (t*B+b) slice 0..255
    const int h   = blockIdx.x & 1;              // half 0/1
    const int tid = threadIdx.x;                 // 0..1023
    const int p0  = (h << 13) + tid * 4;         // base pixel of group 0
    const float* xb = x + (size_t)s * CHANNELS * HW;
    vfloat4 a0, a1;
    {
        const vfloat4* p = (const vfloat4*)(xb + p0);
        a0 = __builtin_nontemporal_load(p);
        a1 = __builtin_nontemporal_load(p + 1024);           // +4096 px
    }
    #pragma unroll 4
    for (int c = 1; c < CHANNELS; ++c) {
        const vfloat4* p = (const vfloat4*)(xb + (size_t)c * HW + p0);
        a0 = v4max(a0, __builtin_nontemporal_load(p));
        a1 = v4max(a1, __builtin_nontemporal_load(p + 1024));
    }
    vfloat4* o = (vfloat4*)(pooled + (size_t)s * HW + p0);
    o[0]    = a0;
    o[1024] = a1;
}

// ---------- kernel 2: lif0 v4 — measured ~37 us (16-CU read-BW floor) ----------
__global__ __launch_bounds__(1024)
void lif0_kernel(const float* __restrict__ pooled, uint8_t* __restrict__ spk) {
    __shared__ uint32_t hist[NB];
    __shared__ uint32_t s_wtot[16];
    __shared__ float    col[CAP];
    __shared__ uint32_t s_sel[4];
    __shared__ float    s_thr;

    const int b    = blockIdx.x;
    const int tid  = threadIdx.x;
    const int wid  = tid >> 6;
    const int lane = tid & 63;

    float m[16];
    #pragma unroll
    for (int i = 0; i < 16; ++i) m[i] = 0.0f;

    hist[tid] = 0; hist[tid + 1024] = 0; hist[tid + 2048] = 0; hist[tid + 3072] = 0;

    const float4* p0 = (const float4*)(pooled + (size_t)b * HW);
    float4 x0 = p0[tid], x1 = p0[1024 + tid], x2 = p0[2048 + tid], x3 = p0[3072 + tid];

    lds_barrier();

    for (int t = 0; t < T_STEPS; ++t) {
        m[ 0] = 0.25f * m[ 0] + x0.x;  m[ 1] = 0.25f * m[ 1] + x0.y;
        m[ 2] = 0.25f * m[ 2] + x0.z;  m[ 3] = 0.25f * m[ 3] + x0.w;
        m[ 4] = 0.25f * m[ 4] + x1.x;  m[ 5] = 0.25f * m[ 5] + x1.y;
        m[ 6] = 0.25f * m[ 6] + x1.z;  m[ 7] = 0.25f * m[ 7] + x1.w;
        m[ 8] = 0.25f * m[ 8] + x2.x;  m[ 9] = 0.25f * m[ 9] + x2.y;
        m[10] = 0.25f * m[10] + x2.z;  m[11] = 0.25f * m[11] + x2.w;
        m[12] = 0.25f * m[12] + x3.x;  m[13] = 0.25f * m[13] + x3.y;
        m[14] = 0.25f * m[14] + x3.z;  m[15] = 0.25f * m[15] + x3.w;

        if (t + 1 < T_STEPS) {
            const float4* pn = (const float4*)(pooled + ((size_t)(t+1) * BATCH + b) * HW);
            x0 = pn[tid]; x1 = pn[1024 + tid]; x2 = pn[2048 + tid]; x3 = pn[3072 + tid];
        }

        float    rlo   = 0.0f;
        float    sc    = NBS;
        uint32_t r     = KSEL;
        uint32_t cnt   = HW;
        uint32_t amask = 0xFFFFu;
        for (int iter = 0;; ++iter) {
            #pragma unroll
            for (int i = 0; i < 16; ++i) {
                if (amask & (1u << i)) {
                    int bn = (int)((m[i] - rlo) * sc);
                    bn = min(max(bn, 0), NB - 1);
                    atomicAdd(&hist[bn], 1u);
                }
            }
            lds_barrier();                               // A
            uint4 hc = *(const uint4*)&hist[tid * 4];
            uint4 z; z.x = z.y = z.z = z.w = 0u;
            *(uint4*)&hist[tid * 4] = z;                 // fold clear
            uint32_t psum = hc.x + hc.y + hc.z + hc.w;
            uint32_t incl = wave_incl_scan(psum, lane);
            if (lane == 63) s_wtot[wid] = incl;
            lds_barrier();                               // B
            uint32_t wbase = 0;
            for (int w = 0; w < wid; ++w) wbase += s_wtot[w];
            uint32_t excl = wbase + incl - psum;
            if (tid == 0) s_sel[3] = 0;
            if (r >= excl && r < excl + psum) {
                uint32_t acc = excl; int dsel = -1; uint32_t nr = 0, nc = 0;
                if (r < acc + hc.x) { dsel = tid*4+0; nr = r-acc; nc = hc.x; } acc += hc.x;
                if (dsel < 0 && r < acc + hc.y) { dsel = tid*4+1; nr = r-acc; nc = hc.y; } acc += hc.y;
                if (dsel < 0 && r < acc + hc.z) { dsel = tid*4+2; nr = r-acc; nc = hc.z; } acc += hc.z;
                if (dsel < 0 && r < acc + hc.w) { dsel = tid*4+3; nr = r-acc; nc = hc.w; }
                s_sel[0] = (uint32_t)dsel; s_sel[1] = nr; s_sel[2] = nc;
            }
            lds_barrier();                               // C
            const int jsel = (int)s_sel[0];
            r = s_sel[1]; cnt = s_sel[2];
            uint32_t nm = 0;
            #pragma unroll
            for (int i = 0; i < 16; ++i) {
                if (amask & (1u << i)) {
                    int bn = (int)((m[i] - rlo) * sc);
                    bn = min(max(bn, 0), NB - 1);
                    if (bn == jsel) nm |= (1u << i);
                }
            }
            amask = nm;
            rlo += (float)jsel / sc;
            sc  *= (float)NB;
            if (cnt <= SMALL || iter >= 3) break;
        }

        #pragma unroll
        for (int i = 0; i < 16; ++i) {
            if (amask & (1u << i)) {
                uint32_t u = atomicAdd(&s_sel[3], 1u);
                if (u < CAP) col[u] = m[i];
            }
        }
        lds_barrier();                                   // D
        {
            uint32_t ncol = min(cnt, (uint32_t)CAP);
            for (uint32_t j = tid; j < ncol; j += 1024) {
                float v = col[j];
                uint32_t less = 0, leq = 0;
                for (uint32_t i2 = 0; i2 < ncol; ++i2) {
                    float u = col[i2];
                    less += (u < v);
                    leq  += (u <= v);
                }
                if (less <= r && r < leq) s_thr = v;     // k-th largest, exact bits
            }
        }
        lds_barrier();                                   // E
        const float thr = s_thr;

        uchar4* so4 = (uchar4*)(spk + ((size_t)t * BATCH + b) * HW);
        #pragma unroll
        for (int i = 0; i < 4; ++i) {
            uchar4 s4;
            s4.x = (m[i*4+0] >= thr) ? 1 : 0;
            s4.y = (m[i*4+1] >= thr) ? 1 : 0;
            s4.z = (m[i*4+2] >= thr) ? 1 : 0;
            s4.w = (m[i*4+3] >= thr) ? 1 : 0;
            if (s4.x) m[i*4+0] = 0.0f;
            if (s4.y) m[i*4+1] = 0.0f;
            if (s4.z) m[i*4+2] = 0.0f;
            if (s4.w) m[i*4+3] = 0.0f;
            so4[i * 1024 + tid] = s4;
        }
    }
}

// ---------- kernel 3: conv v6 — measured best (18.5 us, r12 counters) ----------
__global__ __launch_bounds__(256)
void conv_lif1_kernel(const uint8_t* __restrict__ spk, const float* __restrict__ wconv,
                      float* __restrict__ out_spike, float* __restrict__ out_mem) {
    const int s   = blockIdx.x * 256 + threadIdx.x;  // 0..65535
    const int b   = s >> 12;
    const int rem = s & 4095;
    const int r   = rem >> 5;          // 0..127
    const int c0  = (rem & 31) << 2;   // 0,4,...,124

    float w[49];
    #pragma unroll
    for (int i = 0; i < 49; ++i) w[i] = wconv[i];   // uniform -> SGPRs

    float m0 = 0.f, m1 = 0.f, m2 = 0.f, m3 = 0.f;
    for (int t = 0; t < T_STEPS; ++t) {
        const uint8_t* sb = spk + (((size_t)t * BATCH + b) << 14);
        float a0 = 0.f, a1 = 0.f, a2 = 0.f, a3 = 0.f;
        #pragma unroll
        for (int dy = 0; dy < 7; ++dy) {
            int gr = r + dy - 3;
            uint32_t u0 = 0, u1 = 0, u2 = 0;
            if ((unsigned)gr < (unsigned)HGT) {
                const uint8_t* rp = sb + (gr << 7);
                if (c0 > 0)   u0 = *(const uint32_t*)(rp + c0 - 4);
                u1 = *(const uint32_t*)(rp + c0);
                if (c0 < 124) u2 = *(const uint32_t*)(rp + c0 + 4);
            }
            float win[10];
            win[0] = (float)((u0 >>  8) & 255u);
            win[1] = (float)((u0 >> 16) & 255u);
            win[2] = (float)((u0 >> 24));
            win[3] = (float)( u1         & 255u);
            win[4] = (float)((u1 >>  8) & 255u);
            win[5] = (float)((u1 >> 16) & 255u);
            win[6] = (float)((u1 >> 24));
            win[7] = (float)( u2         & 255u);
            win[8] = (float)((u2 >>  8) & 255u);
            win[9] = (float)((u2 >> 16) & 255u);
            #pragma unroll
            for (int dx = 0; dx < 7; ++dx) {
                float wv = w[dy * 7 + dx];
                a0 = fmaf(win[dx + 0], wv, a0);
                a1 = fmaf(win[dx + 1], wv, a1);
                a2 = fmaf(win[dx + 2], wv, a2);
                a3 = fmaf(win[dx + 3], wv, a3);
            }
        }
        float n0 = 0.25f * m0 + a0;
        float n1 = 0.25f * m1 + a1;
        float n2 = 0.25f * m2 + a2;
        float n3 = 0.25f * m3 + a3;
        float s0 = (n0 > 1.0f) ? 1.0f : 0.0f;
        float s1 = (n1 > 1.0f) ? 1.0f : 0.0f;
        float s2 = (n2 > 1.0f) ? 1.0f : 0.0f;
        float s3 = (n3 > 1.0f) ? 1.0f : 0.0f;
        size_t o = (((size_t)t * BATCH + b) << 14) + ((size_t)r << 7) + c0;
        vfloat4 sv = {s0, s1, s2, s3};
        vfloat4 mv = {n0, n1, n2, n3};
        *(vfloat4*)(out_spike + o) = sv;
        *(vfloat4*)(out_mem   + o) = mv;
        m0 = n0 - s0; m1 = n1 - s1; m2 = n2 - s2; m3 = n3 - s3;
    }
}

extern "C" void kernel_launch(void* const* d_in, const int* in_sizes, int n_in,
                              void* d_out, int out_size, void* d_ws, size_t ws_size,
                              hipStream_t stream) {
    const float* x     = (const float*)d_in[0];
    const float* wconv = (const float*)d_in[1];
    float* out = (float*)d_out;

    const size_t n_pooled = (size_t)T_STEPS * BATCH * HW;
    float*   pooled = (float*)d_ws;
    uint8_t* spk    = (uint8_t*)d_ws + n_pooled * sizeof(float);

    pool_max_kernel<<<512, 1024, 0, stream>>>(x, pooled);
    lif0_kernel<<<BATCH, 1024, 0, stream>>>(pooled, spk);
    conv_lif1_kernel<<<256, 256, 0, stream>>>(spk, wconv, out, out + n_pooled);
}

// Round 19
// 187.808 us; speedup vs baseline: 1.1312x; 1.0333x over previous
//
#include <hip/hip_runtime.h>
#include <hip/hip_bf16.h>
#include <stdint.h>

#define T_STEPS 16
#define BATCH   16
#define CHANNELS 32
#define HGT 128
#define WID 128
#define HW (HGT*WID)      // 16384
#define KSEL 8192         // ascending 0-based rank of threshold = N - k
#define CAP 1024          // candidate buffer (safety)
#define SMALL 128         // stop narrowing when candidate set <= SMALL
#define NB 4096           // histogram bins
#define NBS 1024.0f       // initial scale: 4096 bins over [0,4)

typedef float vfloat4 __attribute__((ext_vector_type(4)));

__device__ __forceinline__ vfloat4 v4max(vfloat4 a, vfloat4 b) {
    vfloat4 r;
    r.x = fmaxf(a.x, b.x); r.y = fmaxf(a.y, b.y);
    r.z = fmaxf(a.z, b.z); r.w = fmaxf(a.w, b.w);
    return r;
}

__device__ __forceinline__ uint32_t wave_incl_scan(uint32_t v, int lane) {
    #pragma unroll
    for (int off = 1; off < 64; off <<= 1) {
        uint32_t u = __shfl_up(v, off, 64);
        if (lane >= off) v += u;
    }
    return v;
}

// LDS-only barrier: drain DS ops, keep global loads in flight.
__device__ __forceinline__ void lds_barrier() {
    asm volatile("s_waitcnt lgkmcnt(0)" ::: "memory");
    __builtin_amdgcn_s_barrier();
}

// ---------- kernel 1: pool v3 — block = one (t,b), sequential plane sweep ----------
// Best measured pool (in-situ ~127 us, r15). 256 blocks x 1024 thr; block
// streams its 2 MB region plane-by-plane with NT loads; 1 block/CU.
__global__ __launch_bounds__(1024)
void pool_max_kernel(const float* __restrict__ x, float* __restrict__ pooled) {
    const int tb  = blockIdx.x;            // 0..255
    const int tid = threadIdx.x;           // 0..1023
    const float* xb = x + (size_t)tb * CHANNELS * HW;
    vfloat4 a0, a1, a2, a3;
    {
        const vfloat4* p = (const vfloat4*)(xb) + tid;
        a0 = __builtin_nontemporal_load(p + 0 * 1024);
        a1 = __builtin_nontemporal_load(p + 1 * 1024);
        a2 = __builtin_nontemporal_load(p + 2 * 1024);
        a3 = __builtin_nontemporal_load(p + 3 * 1024);
    }
    #pragma unroll 4
    for (int c = 1; c < CHANNELS; ++c) {
        const vfloat4* p = (const vfloat4*)(xb + (size_t)c * HW) + tid;
        a0 = v4max(a0, __builtin_nontemporal_load(p + 0 * 1024));
        a1 = v4max(a1, __builtin_nontemporal_load(p + 1 * 1024));
        a2 = v4max(a2, __builtin_nontemporal_load(p + 2 * 1024));
        a3 = v4max(a3, __builtin_nontemporal_load(p + 3 * 1024));
    }
    vfloat4* o = (vfloat4*)(pooled + (size_t)tb * HW) + tid;
    o[0 * 1024] = a0;
    o[1 * 1024] = a1;
    o[2 * 1024] = a2;
    o[3 * 1024] = a3;
}

// ---------- kernel 2: lif0 v4 — measured ~37 us (16-CU read-BW floor) ----------
__global__ __launch_bounds__(1024)
void lif0_kernel(const float* __restrict__ pooled, uint8_t* __restrict__ spk) {
    __shared__ uint32_t hist[NB];
    __shared__ uint32_t s_wtot[16];
    __shared__ float    col[CAP];
    __shared__ uint32_t s_sel[4];
    __shared__ float    s_thr;

    const int b    = blockIdx.x;
    const int tid  = threadIdx.x;
    const int wid  = tid >> 6;
    const int lane = tid & 63;

    float m[16];
    #pragma unroll
    for (int i = 0; i < 16; ++i) m[i] = 0.0f;

    hist[tid] = 0; hist[tid + 1024] = 0; hist[tid + 2048] = 0; hist[tid + 3072] = 0;

    const float4* p0 = (const float4*)(pooled + (size_t)b * HW);
    float4 x0 = p0[tid], x1 = p0[1024 + tid], x2 = p0[2048 + tid], x3 = p0[3072 + tid];

    lds_barrier();

    for (int t = 0; t < T_STEPS; ++t) {
        m[ 0] = 0.25f * m[ 0] + x0.x;  m[ 1] = 0.25f * m[ 1] + x0.y;
        m[ 2] = 0.25f * m[ 2] + x0.z;  m[ 3] = 0.25f * m[ 3] + x0.w;
        m[ 4] = 0.25f * m[ 4] + x1.x;  m[ 5] = 0.25f * m[ 5] + x1.y;
        m[ 6] = 0.25f * m[ 6] + x1.z;  m[ 7] = 0.25f * m[ 7] + x1.w;
        m[ 8] = 0.25f * m[ 8] + x2.x;  m[ 9] = 0.25f * m[ 9] + x2.y;
        m[10] = 0.25f * m[10] + x2.z;  m[11] = 0.25f * m[11] + x2.w;
        m[12] = 0.25f * m[12] + x3.x;  m[13] = 0.25f * m[13] + x3.y;
        m[14] = 0.25f * m[14] + x3.z;  m[15] = 0.25f * m[15] + x3.w;

        if (t + 1 < T_STEPS) {
            const float4* pn = (const float4*)(pooled + ((size_t)(t+1) * BATCH + b) * HW);
            x0 = pn[tid]; x1 = pn[1024 + tid]; x2 = pn[2048 + tid]; x3 = pn[3072 + tid];
        }

        float    rlo   = 0.0f;
        float    sc    = NBS;
        uint32_t r     = KSEL;
        uint32_t cnt   = HW;
        uint32_t amask = 0xFFFFu;
        for (int iter = 0;; ++iter) {
            #pragma unroll
            for (int i = 0; i < 16; ++i) {
                if (amask & (1u << i)) {
                    int bn = (int)((m[i] - rlo) * sc);
                    bn = min(max(bn, 0), NB - 1);
                    atomicAdd(&hist[bn], 1u);
                }
            }
            lds_barrier();                               // A
            uint4 hc = *(const uint4*)&hist[tid * 4];
            uint4 z; z.x = z.y = z.z = z.w = 0u;
            *(uint4*)&hist[tid * 4] = z;                 // fold clear
            uint32_t psum = hc.x + hc.y + hc.z + hc.w;
            uint32_t incl = wave_incl_scan(psum, lane);
            if (lane == 63) s_wtot[wid] = incl;
            lds_barrier();                               // B
            uint32_t wbase = 0;
            for (int w = 0; w < wid; ++w) wbase += s_wtot[w];
            uint32_t excl = wbase + incl - psum;
            if (tid == 0) s_sel[3] = 0;
            if (r >= excl && r < excl + psum) {
                uint32_t acc = excl; int dsel = -1; uint32_t nr = 0, nc = 0;
                if (r < acc + hc.x) { dsel = tid*4+0; nr = r-acc; nc = hc.x; } acc += hc.x;
                if (dsel < 0 && r < acc + hc.y) { dsel = tid*4+1; nr = r-acc; nc = hc.y; } acc += hc.y;
                if (dsel < 0 && r < acc + hc.z) { dsel = tid*4+2; nr = r-acc; nc = hc.z; } acc += hc.z;
                if (dsel < 0 && r < acc + hc.w) { dsel = tid*4+3; nr = r-acc; nc = hc.w; }
                s_sel[0] = (uint32_t)dsel; s_sel[1] = nr; s_sel[2] = nc;
            }
            lds_barrier();                               // C
            const int jsel = (int)s_sel[0];
            r = s_sel[1]; cnt = s_sel[2];
            uint32_t nm = 0;
            #pragma unroll
            for (int i = 0; i < 16; ++i) {
                if (amask & (1u << i)) {
                    int bn = (int)((m[i] - rlo) * sc);
                    bn = min(max(bn, 0), NB - 1);
                    if (bn == jsel) nm |= (1u << i);
                }
            }
            amask = nm;
            rlo += (float)jsel / sc;
            sc  *= (float)NB;
            if (cnt <= SMALL || iter >= 3) break;
        }

        #pragma unroll
        for (int i = 0; i < 16; ++i) {
            if (amask & (1u << i)) {
                uint32_t u = atomicAdd(&s_sel[3], 1u);
                if (u < CAP) col[u] = m[i];
            }
        }
        lds_barrier();                                   // D
        {
            uint32_t ncol = min(cnt, (uint32_t)CAP);
            for (uint32_t j = tid; j < ncol; j += 1024) {
                float v = col[j];
                uint32_t less = 0, leq = 0;
                for (uint32_t i2 = 0; i2 < ncol; ++i2) {
                    float u = col[i2];
                    less += (u < v);
                    leq  += (u <= v);
                }
                if (less <= r && r < leq) s_thr = v;     // k-th largest, exact bits
            }
        }
        lds_barrier();                                   // E
        const float thr = s_thr;

        uchar4* so4 = (uchar4*)(spk + ((size_t)t * BATCH + b) * HW);
        #pragma unroll
        for (int i = 0; i < 4; ++i) {
            uchar4 s4;
            s4.x = (m[i*4+0] >= thr) ? 1 : 0;
            s4.y = (m[i*4+1] >= thr) ? 1 : 0;
            s4.z = (m[i*4+2] >= thr) ? 1 : 0;
            s4.w = (m[i*4+3] >= thr) ? 1 : 0;
            if (s4.x) m[i*4+0] = 0.0f;
            if (s4.y) m[i*4+1] = 0.0f;
            if (s4.z) m[i*4+2] = 0.0f;
            if (s4.w) m[i*4+3] = 0.0f;
            so4[i * 1024 + tid] = s4;
        }
    }
}

// ---------- kernel 3: conv v6 — measured best (18.5 us, r12 counters) ----------
__global__ __launch_bounds__(256)
void conv_lif1_kernel(const uint8_t* __restrict__ spk, const float* __restrict__ wconv,
                      float* __restrict__ out_spike, float* __restrict__ out_mem) {
    const int s   = blockIdx.x * 256 + threadIdx.x;  // 0..65535
    const int b   = s >> 12;
    const int rem = s & 4095;
    const int r   = rem >> 5;          // 0..127
    const int c0  = (rem & 31) << 2;   // 0,4,...,124

    float w[49];
    #pragma unroll
    for (int i = 0; i < 49; ++i) w[i] = wconv[i];   // uniform -> SGPRs

    float m0 = 0.f, m1 = 0.f, m2 = 0.f, m3 = 0.f;
    for (int t = 0; t < T_STEPS; ++t) {
        const uint8_t* sb = spk + (((size_t)t * BATCH + b) << 14);
        float a0 = 0.f, a1 = 0.f, a2 = 0.f, a3 = 0.f;
        #pragma unroll
        for (int dy = 0; dy < 7; ++dy) {
            int gr = r + dy - 3;
            uint32_t u0 = 0, u1 = 0, u2 = 0;
            if ((unsigned)gr < (unsigned)HGT) {
                const uint8_t* rp = sb + (gr << 7);
                if (c0 > 0)   u0 = *(const uint32_t*)(rp + c0 - 4);
                u1 = *(const uint32_t*)(rp + c0);
                if (c0 < 124) u2 = *(const uint32_t*)(rp + c0 + 4);
            }
            float win[10];
            win[0] = (float)((u0 >>  8) & 255u);
            win[1] = (float)((u0 >> 16) & 255u);
            win[2] = (float)((u0 >> 24));
            win[3] = (float)( u1         & 255u);
            win[4] = (float)((u1 >>  8) & 255u);
            win[5] = (float)((u1 >> 16) & 255u);
            win[6] = (float)((u1 >> 24));
            win[7] = (float)( u2         & 255u);
            win[8] = (float)((u2 >>  8) & 255u);
            win[9] = (float)((u2 >> 16) & 255u);
            #pragma unroll
            for (int dx = 0; dx < 7; ++dx) {
                float wv = w[dy * 7 + dx];
                a0 = fmaf(win[dx + 0], wv, a0);
                a1 = fmaf(win[dx + 1], wv, a1);
                a2 = fmaf(win[dx + 2], wv, a2);
                a3 = fmaf(win[dx + 3], wv, a3);
            }
        }
        float n0 = 0.25f * m0 + a0;
        float n1 = 0.25f * m1 + a1;
        float n2 = 0.25f * m2 + a2;
        float n3 = 0.25f * m3 + a3;
        float s0 = (n0 > 1.0f) ? 1.0f : 0.0f;
        float s1 = (n1 > 1.0f) ? 1.0f : 0.0f;
        float s2 = (n2 > 1.0f) ? 1.0f : 0.0f;
        float s3 = (n3 > 1.0f) ? 1.0f : 0.0f;
        size_t o = (((size_t)t * BATCH + b) << 14) + ((size_t)r << 7) + c0;
        vfloat4 sv = {s0, s1, s2, s3};
        vfloat4 mv = {n0, n1, n2, n3};
        *(vfloat4*)(out_spike + o) = sv;
        *(vfloat4*)(out_mem   + o) = mv;
        m0 = n0 - s0; m1 = n1 - s1; m2 = n2 - s2; m3 = n3 - s3;
    }
}

extern "C" void kernel_launch(void* const* d_in, const int* in_sizes, int n_in,
                              void* d_out, int out_size, void* d_ws, size_t ws_size,
                              hipStream_t stream) {
    const float* x     = (const float*)d_in[0];
    const float* wconv = (const float*)d_in[1];
    float* out = (float*)d_out;

    const size_t n_pooled = (size_t)T_STEPS * BATCH * HW;
    float*   pooled = (float*)d_ws;
    uint8_t* spk    = (uint8_t*)d_ws + n_pooled * sizeof(float);

    pool_max_kernel<<<256, 1024, 0, stream>>>(x, pooled);
    lif0_kernel<<<BATCH, 1024, 0, stream>>>(pooled, spk);
    conv_lif1_kernel<<<256, 256, 0, stream>>>(spk, wconv, out, out + n_pooled);
}